// Round 6
// baseline (390.401 us; speedup 1.0000x reference)
//
#include <hip/hip_runtime.h>
#include <hip/hip_bf16.h>

// Problem constants
#define DIMN   2048
#define NH     16
#define NKVH   4
#define HD     128
#define KVD    512        // NKVH*HD
#define NQKV   3072       // DIMN + 2*KVD
#define BATCH  2
#define SEQ    2048
#define MROWS  4096       // BATCH*SEQ
#define VOFF   2560       // DIMN + KVD: v offset inside qkv row

typedef __attribute__((ext_vector_type(8))) __bf16 bf16x8;
typedef __attribute__((ext_vector_type(4))) float floatx4;

#define BIG_NEG (-1.0e30f)

__device__ __forceinline__ short bf16rn(float f) {
  union { float f; unsigned u; } v; v.f = f;
  unsigned u = v.u;
  return (short)((u + 0x7fffu + ((u >> 16) & 1u)) >> 16);
}

// async 16B global -> LDS. Contract: LDS dest = wave-uniform base + lane*16 BYTES;
// one instruction covers 64 lanes * 16 B = 1024 B = 512 shorts.
__device__ __forceinline__ void async_cp16(const short* g, short* l) {
  __builtin_amdgcn_global_load_lds(
      (const __attribute__((address_space(1))) unsigned int*)g,
      (__attribute__((address_space(3))) unsigned int*)l, 16, 0, 0);
}

// ---------------------------------------------------------------- f32 -> bf16
__global__ void f32_to_bf16_kern(const float* __restrict__ in,
                                 short* __restrict__ out, int n8) {
  int i = blockIdx.x * blockDim.x + threadIdx.x;
  if (i >= n8) return;
  float4 a = ((const float4*)in)[i * 2];
  float4 b = ((const float4*)in)[i * 2 + 1];
  short r[8];
  r[0] = bf16rn(a.x); r[1] = bf16rn(a.y); r[2] = bf16rn(a.z); r[3] = bf16rn(a.w);
  r[4] = bf16rn(b.x); r[5] = bf16rn(b.y); r[6] = bf16rn(b.z); r[7] = bf16rn(b.w);
  ((uint4*)out)[i] = *(const uint4*)r;
}

// --------------------------------------------------- C[M][N] = A[M][K] B[N][K]^T
// 128x128 tile, BK=32, DOUBLE-BUFFERED global_load_lds staging with a single
// barrier per K-iter: barrier(i) drains stage(i) issued during iter i-1 while
// iter i-1's frag-reads+MFMA overlapped the latency. XOR-swizzled LDS
// (stored chunk = logical ^ (row&3)); frag reads conflict-free per 8-lane group.
__global__ __launch_bounds__(256) void gemm_bt_as(const short* __restrict__ A,
                                                  const short* __restrict__ Bw,
                                                  float* __restrict__ C,
                                                  int N, int K) {
  __shared__ __align__(16) short As[2][128 * 32];   // 2 x 8 KB
  __shared__ __align__(16) short Bs[2][128 * 32];
  const int t = threadIdx.x;
  const int lane = t & 63, wave = t >> 6;
  const int lrow = lane & 15, quad = lane >> 4;
  const int wr = wave >> 1, wc = wave & 1;
  const int m0 = blockIdx.y * 128, n0 = blockIdx.x * 128;

  // staging: inst wi = wave*2+i covers rows wi*16..+15 (512 shorts)
  // lane l: row = wi*16 + (l>>2), stored chunk s = l&3, logical c = s ^ (row&3)
  const short* pa[2];
  const short* pb[2];
  int wi2[2];
#pragma unroll
  for (int i = 0; i < 2; i++) {
    int wi = wave * 2 + i;
    int row = wi * 16 + (lane >> 2);
    int col = ((lane & 3) ^ (row & 3)) * 8;
    pa[i] = A + (size_t)(m0 + row) * K + col;
    pb[i] = Bw + (size_t)(n0 + row) * K + col;
    wi2[i] = wi;
  }

  floatx4 acc[4][4] = {};
  const int iters = K >> 5;

  // prologue: stage iter 0 into buf 0
#pragma unroll
  for (int i = 0; i < 2; i++) {
    async_cp16(pa[i], &As[0][wi2[i] * 512]);
    async_cp16(pb[i], &Bs[0][wi2[i] * 512]);
  }

  for (int it = 0; it < iters; it++) {
    const int cur = it & 1;
    __syncthreads();   // drains stage(it); prior iter's reads of buf[cur^1] done

    if (it + 1 < iters) {
      const int off = (it + 1) * 32;
#pragma unroll
      for (int i = 0; i < 2; i++) {
        async_cp16(pa[i] + off, &As[cur ^ 1][wi2[i] * 512]);
        async_cp16(pb[i] + off, &Bs[cur ^ 1][wi2[i] * 512]);
      }
    }

    bf16x8 af[4], bfr[4];
#pragma unroll
    for (int mt = 0; mt < 4; mt++) {
      int row = wr * 64 + mt * 16 + lrow;
      af[mt] = *(const bf16x8*)&As[cur][row * 32 + (quad ^ (lrow & 3)) * 8];
    }
#pragma unroll
    for (int nt = 0; nt < 4; nt++) {
      int row = wc * 64 + nt * 16 + lrow;
      bfr[nt] = *(const bf16x8*)&Bs[cur][row * 32 + (quad ^ (lrow & 3)) * 8];
    }
#pragma unroll
    for (int mt = 0; mt < 4; mt++)
#pragma unroll
      for (int nt = 0; nt < 4; nt++)
        acc[mt][nt] = __builtin_amdgcn_mfma_f32_16x16x32_bf16(af[mt], bfr[nt],
                                                              acc[mt][nt], 0, 0, 0);
  }

#pragma unroll
  for (int mt = 0; mt < 4; mt++)
#pragma unroll
    for (int nt = 0; nt < 4; nt++) {
      int row = m0 + wr * 64 + mt * 16 + quad * 4;
      int col = n0 + wc * 64 + nt * 16 + lrow;
#pragma unroll
      for (int r = 0; r < 4; r++)
        C[(size_t)(row + r) * N + col] = acc[mt][nt][r];
    }
}

// -------------------------------------------- per-(row,head): RMSNorm+RoPE+gain
// one wave per (row, slot): slots 0..15 = q heads, 16..19 = k heads (v handled by vT_kern)
__global__ __launch_bounds__(256) void rms_rope_kern(const float* __restrict__ qkv,
                                                     const float* __restrict__ gain,
                                                     short* __restrict__ qb,
                                                     short* __restrict__ kb) {
  const int t = threadIdx.x;
  const int lane = t & 63, wave = t >> 6;
  const int gw = blockIdx.x * 4 + wave;
  const int row = gw / 20, slot = gw - row * 20;
  const int pos = row & (SEQ - 1);

  const float* src = (slot < 16) ? qkv + (size_t)row * NQKV + slot * HD
                                 : qkv + (size_t)row * NQKV + DIMN + (slot - 16) * HD;
  float x1 = src[lane], x2 = src[lane + 64];

  float ss = x1 * x1 + x2 * x2;
#pragma unroll
  for (int off = 32; off > 0; off >>= 1) ss += __shfl_xor(ss, off);
  float inv = rsqrtf(ss * (1.0f / 128.0f) + 1.1920928955078125e-7f);
  x1 *= inv; x2 *= inv;
  float fr = (float)pos * exp2f((float)lane * -0.20762050593045935f);
  float s, c;
  sincosf(fr, &s, &c);
  float y1 = x1 * c + x2 * s;
  float y2 = x2 * c - x1 * s;
  if (slot < 16) {
    // q_gain * 1/sqrt(HD) * log2(e): softmax then uses exp2 directly
    float g = gain[slot] * 0.12751744459132754f;
    y1 *= g; y2 *= g;
  }
  short o1 = bf16rn(y1), o2 = bf16rn(y2);
  if (slot < 16) { short* d = qb + (size_t)row * DIMN + slot * HD;        d[lane] = o1; d[lane + 64] = o2; }
  else           { short* d = kb + (size_t)row * KVD + (slot - 16) * HD;  d[lane] = o1; d[lane + 64] = o2; }
}

// ------------------------------------- v transpose: qkv f32 [t][d] -> vT bf16 [d][t]
__global__ __launch_bounds__(256) void vT_kern(const float* __restrict__ qkv,
                                               short* __restrict__ vT) {
  __shared__ short L[64 * 68];
  const int t0 = blockIdx.x * 64, d0 = blockIdx.y * 64;
  const int b = blockIdx.z >> 2, kvh = blockIdx.z & 3;
  const int t = threadIdx.x;

#pragma unroll
  for (int p = 0; p < 4; p++) {
    int tt = p * 16 + (t >> 4);
    int dd = (t & 15) * 4;
    float4 f = *(const float4*)(qkv + (size_t)(b * SEQ + t0 + tt) * NQKV + VOFF + kvh * HD + d0 + dd);
    short s4[4] = { bf16rn(f.x), bf16rn(f.y), bf16rn(f.z), bf16rn(f.w) };
    *(ushort4*)&L[tt * 68 + dd] = *(const ushort4*)s4;
  }
  __syncthreads();

  const int dl = t >> 2;
  const int tc = (t & 3) * 16;
  short tmp[16];
#pragma unroll
  for (int j = 0; j < 16; j++) tmp[j] = L[(tc + j) * 68 + dl];
  size_t obase = (size_t)((b * NKVH + kvh) * HD + d0 + dl) * SEQ + t0 + tc;
  *(uint4*)(vT + obase)     = ((const uint4*)tmp)[0];
  *(uint4*)(vT + obase + 8) = ((const uint4*)tmp)[1];
}

// ------------------------------------------------------- causal flash attention
// grid (16 qpair, 16 g), 256 threads = 4 waves; wave = (h, rg) owns 32 Q-rows of
// one head => bk/bv frag reads amortize over 2x rows (144 vs 272 b128/block/kt).
// 66 KB LDS => 2 blocks/CU (cross-block latency hiding). K double-buffered;
// V staged at tile start, drained at barrier-2 after softmax (hidden behind S).
// qt-pairing {qp, 31-qp}: uniform 33 K-tiles/block.
__global__ __launch_bounds__(256) void attn_kern(const short* __restrict__ qb,
                                                 const short* __restrict__ kb,
                                                 const short* __restrict__ vT,
                                                 short* __restrict__ yb) {
  __shared__ __align__(16) short Ks[2][64 * 128];   // 32 KB [row][chunk^(row&7)]
  __shared__ __align__(16) short Vs[128 * 64];      // 16 KB [d][chunk^(d&7)]
  __shared__ __align__(16) short Ps[128 * 72];      // 18 KB wave-private strips
  const int qp = blockIdx.x;
  const int g  = blockIdx.y;
  const int b = g >> 3, kvh = (g >> 1) & 3, hp = g & 1;
  const int h0 = kvh * 4 + hp * 2;
  const int t = threadIdx.x, lane = t & 63, wave = t >> 6;
  const int h = wave & 1, rg = wave >> 1;        // head, row-group (32 rows)
  const int lrow = lane & 15, quad = lane >> 4;

  // staging geometry: per wave inst wi = wave*4 + i (0..15)
  int k_row[4], k_col[4], v_row[4], v_col[4];
#pragma unroll
  for (int i = 0; i < 4; i++) {
    int wi = wave * 4 + i;
    int kr = wi * 4 + (lane >> 4);
    k_row[i] = kr; k_col[i] = ((lane & 15) ^ (kr & 7)) * 8;
    int vr = wi * 8 + (lane >> 3);
    v_row[i] = vr; v_col[i] = ((lane & 7) ^ (vr & 7)) * 8;
  }
  const short* kbase = kb + (size_t)b * SEQ * KVD + kvh * HD;
  const short* vbase = vT + (size_t)(b * NKVH + kvh) * HD * SEQ;

  for (int ph = 0; ph < 2; ph++) {
    const int qt = ph ? (31 - qp) : qp;
    const int q0 = qt * 64;

    __syncthreads();  // all waves done with previous phase's LDS

    // Q fragments in registers (1/sqrt(d), gain, log2e folded in)
    bf16x8 aq[2][4];
#pragma unroll
    for (int mt = 0; mt < 2; mt++) {
      const short* qrow = qb + (size_t)(b * SEQ + q0 + rg * 32 + mt * 16 + lrow) * DIMN
                             + (h0 + h) * HD;
#pragma unroll
      for (int kk = 0; kk < 4; kk++)
        aq[mt][kk] = *(const bf16x8*)(qrow + kk * 32 + quad * 8);
    }

    floatx4 O[2][8] = {};
    float mI[2][4], lI[2][4];
#pragma unroll
    for (int mt = 0; mt < 2; mt++)
#pragma unroll
      for (int r = 0; r < 4; r++) { mI[mt][r] = BIG_NEG; lI[mt][r] = 0.0f; }

    // prologue: stage K(0) into buf 0
#pragma unroll
    for (int i = 0; i < 4; i++)
      async_cp16(kbase + (size_t)k_row[i] * KVD + k_col[i], &Ks[0][(wave * 4 + i) * 512]);

    for (int kt = 0; kt <= qt; kt++) {
      const int cur = kt & 1;
      const int k0 = kt * 64;
      __syncthreads();  // drains K(kt); all waves done with Vs(kt-1) reads

      // stage V(kt) and K(kt+1); drained at barrier-2 (hidden behind S+softmax)
#pragma unroll
      for (int i = 0; i < 4; i++)
        async_cp16(vbase + (size_t)v_row[i] * SEQ + k0 + v_col[i], &Vs[(wave * 4 + i) * 512]);
      if (kt < qt) {
        const int kn = k0 + 64;
#pragma unroll
        for (int i = 0; i < 4; i++)
          async_cp16(kbase + (size_t)(kn + k_row[i]) * KVD + k_col[i],
                     &Ks[cur ^ 1][(wave * 4 + i) * 512]);
      }

      // S = Q K^T: 32 rows/wave, bk frags shared across the 2 row-groups
      floatx4 S[2][4] = {};
#pragma unroll
      for (int kk = 0; kk < 4; kk++)
#pragma unroll
        for (int nt = 0; nt < 4; nt++) {
          int row = nt * 16 + lrow;
          bf16x8 bk = *(const bf16x8*)&Ks[cur][row * 128 + ((kk * 4 + quad) ^ (row & 7)) * 8];
          S[0][nt] = __builtin_amdgcn_mfma_f32_16x16x32_bf16(aq[0][kk], bk, S[0][nt], 0, 0, 0);
          S[1][nt] = __builtin_amdgcn_mfma_f32_16x16x32_bf16(aq[1][kk], bk, S[1][nt], 0, 0, 0);
        }

      if (kt == qt) {  // diagonal: causal mask
#pragma unroll
        for (int mt = 0; mt < 2; mt++)
#pragma unroll
          for (int nt = 0; nt < 4; nt++) {
            int kj = nt * 16 + lrow;
#pragma unroll
            for (int r = 0; r < 4; r++) {
              int qi = rg * 32 + mt * 16 + quad * 4 + r;
              if (kj > qi) S[mt][nt][r] = BIG_NEG;
            }
          }
      }

      // online softmax (exp2 domain) + P pack into wave-private LDS strip
#pragma unroll
      for (int mt = 0; mt < 2; mt++) {
#pragma unroll
        for (int r = 0; r < 4; r++) {
          float mx = fmaxf(fmaxf(S[mt][0][r], S[mt][1][r]), fmaxf(S[mt][2][r], S[mt][3][r]));
          mx = fmaxf(mx, __shfl_xor(mx, 1));
          mx = fmaxf(mx, __shfl_xor(mx, 2));
          mx = fmaxf(mx, __shfl_xor(mx, 4));
          mx = fmaxf(mx, __shfl_xor(mx, 8));
          float mNew = fmaxf(mI[mt][r], mx);
          float alpha = exp2f(mI[mt][r] - mNew);
          float ssum = 0.0f;
#pragma unroll
          for (int nt = 0; nt < 4; nt++) {
            float p = exp2f(S[mt][nt][r] - mNew);
            S[mt][nt][r] = p;
            ssum += p;
          }
          ssum += __shfl_xor(ssum, 1);
          ssum += __shfl_xor(ssum, 2);
          ssum += __shfl_xor(ssum, 4);
          ssum += __shfl_xor(ssum, 8);
          lI[mt][r] = lI[mt][r] * alpha + ssum;
          mI[mt][r] = mNew;
#pragma unroll
          for (int n2 = 0; n2 < 8; n2++) O[mt][n2][r] *= alpha;
        }
#pragma unroll
        for (int nt = 0; nt < 4; nt++) {
          int cwr = ((nt * 2 + (lrow >> 3)) ^ (quad * 2)) * 8 + (lrow & 7);
#pragma unroll
          for (int r = 0; r < 4; r++)
            Ps[(wave * 32 + mt * 16 + quad * 4 + r) * 72 + cwr] = bf16rn(S[mt][nt][r]);
        }
      }

      __syncthreads();  // drains V(kt) (+K(kt+1)); Vs ready

      // O += P V ; bv frags shared across the 2 row-groups
#pragma unroll
      for (int kk = 0; kk < 2; kk++) {
        int capc = ((kk * 4 + quad) ^ (2 * ((lrow >> 2) & 3))) * 8;
        bf16x8 ap0 = *(const bf16x8*)&Ps[(wave * 32 + lrow) * 72 + capc];
        bf16x8 ap1 = *(const bf16x8*)&Ps[(wave * 32 + 16 + lrow) * 72 + capc];
#pragma unroll
        for (int n2 = 0; n2 < 8; n2++) {
          int row = n2 * 16 + lrow;
          bf16x8 bv = *(const bf16x8*)&Vs[row * 64 + ((kk * 4 + quad) ^ (row & 7)) * 8];
          O[0][n2] = __builtin_amdgcn_mfma_f32_16x16x32_bf16(ap0, bv, O[0][n2], 0, 0, 0);
          O[1][n2] = __builtin_amdgcn_mfma_f32_16x16x32_bf16(ap1, bv, O[1][n2], 0, 0, 0);
        }
      }
    }

    // epilogue: this wave's 32 rows x 128 dims of head h0+h
#pragma unroll
    for (int mt = 0; mt < 2; mt++)
#pragma unroll
      for (int n2 = 0; n2 < 8; n2++)
#pragma unroll
        for (int r = 0; r < 4; r++) {
          float val = O[mt][n2][r] / lI[mt][r];
          int row = q0 + rg * 32 + mt * 16 + quad * 4 + r;
          int col = (h0 + h) * HD + n2 * 16 + lrow;
          yb[(size_t)(b * SEQ + row) * DIMN + col] = bf16rn(val);
        }
  }
}

// ----------------------------------------------------------------- launch
extern "C" void kernel_launch(void* const* d_in, const int* in_sizes, int n_in,
                              void* d_out, int out_size, void* d_ws, size_t ws_size,
                              hipStream_t stream) {
  const float* x      = (const float*)d_in[0];
  const float* q_gain = (const float*)d_in[1];
  const float* W_q    = (const float*)d_in[2];
  const float* W_k    = (const float*)d_in[3];
  const float* W_v    = (const float*)d_in[4];
  const float* W_proj = (const float*)d_in[5];
  float* out = (float*)d_out;
  char* ws = (char*)d_ws;

  short* xb    = (short*)(ws);                // MROWS*DIMN bf16
  short* wqkv  = (short*)(ws + 16777216);     // NQKV*DIMN bf16
  short* wproj = (short*)(ws + 29360128);     // DIMN*DIMN bf16
  float* qkv   = (float*)(ws + 37748736);     // MROWS*NQKV f32
  short* q     = (short*)(ws + 88080384);     // MROWS*DIMN bf16
  short* k     = (short*)(ws + 104857600);    // MROWS*KVD bf16
  short* vT    = (short*)(ws + 109051904);    // NKVH-major transposed V bf16
  short* y     = xb;                          // alias: xb dead after QKV GEMM

  auto cvt = [&](const float* src, short* dst, int n) {
    int n8 = n / 8;
    f32_to_bf16_kern<<<(n8 + 255) / 256, 256, 0, stream>>>(src, dst, n8);
  };
  cvt(x, xb, MROWS * DIMN);
  cvt(W_q, wqkv, DIMN * DIMN);
  cvt(W_k, wqkv + DIMN * DIMN, KVD * DIMN);
  cvt(W_v, wqkv + DIMN * DIMN + KVD * DIMN, KVD * DIMN);
  cvt(W_proj, wproj, DIMN * DIMN);

  gemm_bt_as<<<dim3(NQKV / 128, MROWS / 128), 256, 0, stream>>>(xb, wqkv, qkv, NQKV, DIMN);
  rms_rope_kern<<<(MROWS * 20) / 4, 256, 0, stream>>>(qkv, q_gain, q, k);
  vT_kern<<<dim3(SEQ / 64, HD / 64, BATCH * NKVH), 256, 0, stream>>>(qkv, vT);
  attn_kern<<<dim3(16, 16), 256, 0, stream>>>(q, k, vT, y);
  gemm_bt_as<<<dim3(DIMN / 128, MROWS / 128), 256, 0, stream>>>(y, wproj, out, DIMN, DIMN);
}

// Round 7
// 349.220 us; speedup vs baseline: 1.1179x; 1.1179x over previous
//
#include <hip/hip_runtime.h>
#include <hip/hip_bf16.h>
#include <type_traits>

// Problem constants
#define DIMN   2048
#define NH     16
#define NKVH   4
#define HD     128
#define KVD    512        // NKVH*HD
#define NQKV   3072       // DIMN + 2*KVD
#define BATCH  2
#define SEQ    2048
#define MROWS  4096       // BATCH*SEQ
#define VOFF   2560       // DIMN + KVD: v offset inside qkv row

typedef __attribute__((ext_vector_type(8))) __bf16 bf16x8;
typedef __attribute__((ext_vector_type(4))) float floatx4;

#define BIG_NEG (-1.0e30f)

__device__ __forceinline__ short bf16rn(float f) {
  union { float f; unsigned u; } v; v.f = f;
  unsigned u = v.u;
  return (short)((u + 0x7fffu + ((u >> 16) & 1u)) >> 16);
}
__device__ __forceinline__ float bf2f(short s) {
  union { unsigned u; float f; } v;
  v.u = ((unsigned)(unsigned short)s) << 16;
  return v.f;
}

// async 16B global -> LDS. LDS dest = wave-uniform base + lane*16 B;
// one instruction covers 64 lanes * 16 B = 512 shorts.
__device__ __forceinline__ void async_cp16(const short* g, short* l) {
  __builtin_amdgcn_global_load_lds(
      (const __attribute__((address_space(1))) unsigned int*)g,
      (__attribute__((address_space(3))) unsigned int*)l, 16, 0, 0);
}

// ---------------------------------------------------------------- f32 -> bf16
__global__ void f32_to_bf16_kern(const float* __restrict__ in,
                                 short* __restrict__ out, int n8) {
  int i = blockIdx.x * blockDim.x + threadIdx.x;
  if (i >= n8) return;
  float4 a = ((const float4*)in)[i * 2];
  float4 b = ((const float4*)in)[i * 2 + 1];
  short r[8];
  r[0] = bf16rn(a.x); r[1] = bf16rn(a.y); r[2] = bf16rn(a.z); r[3] = bf16rn(a.w);
  r[4] = bf16rn(b.x); r[5] = bf16rn(b.y); r[6] = bf16rn(b.z); r[7] = bf16rn(b.w);
  ((uint4*)out)[i] = *(const uint4*)r;
}

// --------------------------------------------------- C[M][N] = A[M][K] B[N][K]^T
// 128x128 tile, BK=32, double-buffered global_load_lds staging, one barrier per
// K-iter. XOR-swizzled LDS (stored chunk = logical ^ (row&3)). OUT: float or
// bf16 (short) epilogue.
template <typename OUT>
__global__ __launch_bounds__(256) void gemm_bt_as(const short* __restrict__ A,
                                                  const short* __restrict__ Bw,
                                                  OUT* __restrict__ C,
                                                  int N, int K) {
  __shared__ __align__(16) short As[2][128 * 32];
  __shared__ __align__(16) short Bs[2][128 * 32];
  const int t = threadIdx.x;
  const int lane = t & 63, wave = t >> 6;
  const int lrow = lane & 15, quad = lane >> 4;
  const int wr = wave >> 1, wc = wave & 1;
  const int m0 = blockIdx.y * 128, n0 = blockIdx.x * 128;

  const short* pa[2];
  const short* pb[2];
  int wi2[2];
#pragma unroll
  for (int i = 0; i < 2; i++) {
    int wi = wave * 2 + i;
    int row = wi * 16 + (lane >> 2);
    int col = ((lane & 3) ^ (row & 3)) * 8;
    pa[i] = A + (size_t)(m0 + row) * K + col;
    pb[i] = Bw + (size_t)(n0 + row) * K + col;
    wi2[i] = wi;
  }

  floatx4 acc[4][4] = {};
  const int iters = K >> 5;

#pragma unroll
  for (int i = 0; i < 2; i++) {
    async_cp16(pa[i], &As[0][wi2[i] * 512]);
    async_cp16(pb[i], &Bs[0][wi2[i] * 512]);
  }

  for (int it = 0; it < iters; it++) {
    const int cur = it & 1;
    __syncthreads();   // drains stage(it); prior iter's reads of buf[cur^1] done

    if (it + 1 < iters) {
      const int off = (it + 1) * 32;
#pragma unroll
      for (int i = 0; i < 2; i++) {
        async_cp16(pa[i] + off, &As[cur ^ 1][wi2[i] * 512]);
        async_cp16(pb[i] + off, &Bs[cur ^ 1][wi2[i] * 512]);
      }
    }

    bf16x8 af[4], bfr[4];
#pragma unroll
    for (int mt = 0; mt < 4; mt++) {
      int row = wr * 64 + mt * 16 + lrow;
      af[mt] = *(const bf16x8*)&As[cur][row * 32 + (quad ^ (lrow & 3)) * 8];
    }
#pragma unroll
    for (int nt = 0; nt < 4; nt++) {
      int row = wc * 64 + nt * 16 + lrow;
      bfr[nt] = *(const bf16x8*)&Bs[cur][row * 32 + (quad ^ (lrow & 3)) * 8];
    }
#pragma unroll
    for (int mt = 0; mt < 4; mt++)
#pragma unroll
      for (int nt = 0; nt < 4; nt++)
        acc[mt][nt] = __builtin_amdgcn_mfma_f32_16x16x32_bf16(af[mt], bfr[nt],
                                                              acc[mt][nt], 0, 0, 0);
  }

#pragma unroll
  for (int mt = 0; mt < 4; mt++)
#pragma unroll
    for (int nt = 0; nt < 4; nt++) {
      int row = m0 + wr * 64 + mt * 16 + quad * 4;
      int col = n0 + wc * 64 + nt * 16 + lrow;
#pragma unroll
      for (int r = 0; r < 4; r++) {
        if constexpr (std::is_same<OUT, short>::value)
          C[(size_t)(row + r) * N + col] = bf16rn(acc[mt][nt][r]);
        else
          C[(size_t)(row + r) * N + col] = acc[mt][nt][r];
      }
    }
}

// -------------------------------------------- per-(row,head): RMSNorm+RoPE+gain
// qkv now bf16. one wave per (row, slot): slots 0..15 = q heads, 16..19 = k heads
__global__ __launch_bounds__(256) void rms_rope_kern(const short* __restrict__ qkv,
                                                     const float* __restrict__ gain,
                                                     short* __restrict__ qb,
                                                     short* __restrict__ kb) {
  const int t = threadIdx.x;
  const int lane = t & 63, wave = t >> 6;
  const int gw = blockIdx.x * 4 + wave;
  const int row = gw / 20, slot = gw - row * 20;
  const int pos = row & (SEQ - 1);

  const short* src = (slot < 16) ? qkv + (size_t)row * NQKV + slot * HD
                                 : qkv + (size_t)row * NQKV + DIMN + (slot - 16) * HD;
  float x1 = bf2f(src[lane]), x2 = bf2f(src[lane + 64]);

  float ss = x1 * x1 + x2 * x2;
#pragma unroll
  for (int off = 32; off > 0; off >>= 1) ss += __shfl_xor(ss, off);
  float inv = rsqrtf(ss * (1.0f / 128.0f) + 1.1920928955078125e-7f);
  x1 *= inv; x2 *= inv;
  float fr = (float)pos * exp2f((float)lane * -0.20762050593045935f);
  float s, c;
  sincosf(fr, &s, &c);
  float y1 = x1 * c + x2 * s;
  float y2 = x2 * c - x1 * s;
  if (slot < 16) {
    // q_gain * 1/sqrt(HD) * log2(e): softmax then uses exp2 directly
    float g = gain[slot] * 0.12751744459132754f;
    y1 *= g; y2 *= g;
  }
  short o1 = bf16rn(y1), o2 = bf16rn(y2);
  if (slot < 16) { short* d = qb + (size_t)row * DIMN + slot * HD;        d[lane] = o1; d[lane + 64] = o2; }
  else           { short* d = kb + (size_t)row * KVD + (slot - 16) * HD;  d[lane] = o1; d[lane + 64] = o2; }
}

// ------------------------------------- v transpose: qkv bf16 [t][d] -> vT bf16 [d][t]
__global__ __launch_bounds__(256) void vT_kern(const short* __restrict__ qkv,
                                               short* __restrict__ vT) {
  __shared__ short L[64 * 68];
  const int t0 = blockIdx.x * 64, d0 = blockIdx.y * 64;
  const int b = blockIdx.z >> 2, kvh = blockIdx.z & 3;
  const int t = threadIdx.x;

#pragma unroll
  for (int p = 0; p < 4; p++) {
    int tt = p * 16 + (t >> 4);
    int dd = (t & 15) * 4;
    ushort4 v = *(const ushort4*)(qkv + (size_t)(b * SEQ + t0 + tt) * NQKV + VOFF + kvh * HD + d0 + dd);
    *(ushort4*)&L[tt * 68 + dd] = v;
  }
  __syncthreads();

  const int dl = t >> 2;
  const int tc = (t & 3) * 16;
  short tmp[16];
#pragma unroll
  for (int j = 0; j < 16; j++) tmp[j] = L[(tc + j) * 68 + dl];
  size_t obase = (size_t)((b * NKVH + kvh) * HD + d0 + dl) * SEQ + t0 + tc;
  *(uint4*)(vT + obase)     = ((const uint4*)tmp)[0];
  *(uint4*)(vT + obase + 8) = ((const uint4*)tmp)[1];
}

// ------------------------------------------------------- causal flash attention
// grid (16 qp, 32 bh) = 512 blocks, 256 threads (4 waves x 16 Q-rows), 57 KB LDS
// => 2 blocks/CU = 8 waves/CU, with INDEPENDENT barriers per block (one block's
// staging drain overlaps the other's compute). Block: 64 Q-rows x 1 head;
// qt-paired phases {qp, 31-qp} = uniform 33 K-tiles/block. K double-buffered;
// V staged at tile start, drained at barrier-2 (hidden behind S+softmax).
__global__ __launch_bounds__(256) void attn_kern(const short* __restrict__ qb,
                                                 const short* __restrict__ kb,
                                                 const short* __restrict__ vT,
                                                 short* __restrict__ yb) {
  __shared__ __align__(16) short Ks[2][64 * 128];   // 32 KB [row][chunk^(row&7)]
  __shared__ __align__(16) short Vs[128 * 64];      // 16 KB [d][chunk^(d&7)]
  __shared__ __align__(16) short Ps[64 * 72];       //  9 KB wave-private strips
  const int qp = blockIdx.x;
  const int g  = blockIdx.y;
  const int b = g >> 4, h = g & 15, kvh = h >> 2;
  const int t = threadIdx.x, lane = t & 63, wave = t >> 6;
  const int lrow = lane & 15, quad = lane >> 4;

  // staging geometry: per wave inst wi = wave*4 + i (0..15)
  int k_row[4], k_col[4], v_row[4], v_col[4];
#pragma unroll
  for (int i = 0; i < 4; i++) {
    int wi = wave * 4 + i;
    int kr = wi * 4 + (lane >> 4);
    k_row[i] = kr; k_col[i] = ((lane & 15) ^ (kr & 7)) * 8;
    int vr = wi * 8 + (lane >> 3);
    v_row[i] = vr; v_col[i] = ((lane & 7) ^ (vr & 7)) * 8;
  }
  const short* kbase = kb + (size_t)b * SEQ * KVD + kvh * HD;
  const short* vbase = vT + (size_t)(b * NKVH + kvh) * HD * SEQ;

  for (int ph = 0; ph < 2; ph++) {
    const int qt = ph ? (31 - qp) : qp;
    const int q0 = qt * 64;

    __syncthreads();  // all waves done with previous phase's LDS

    // Q fragments in registers (1/sqrt(d), gain, log2e folded in)
    bf16x8 aq[4];
    const short* qrow = qb + (size_t)(b * SEQ + q0 + wave * 16 + lrow) * DIMN + h * HD;
#pragma unroll
    for (int kk = 0; kk < 4; kk++)
      aq[kk] = *(const bf16x8*)(qrow + kk * 32 + quad * 8);

    floatx4 O[8] = {};
    float mI[4], lI[4];
#pragma unroll
    for (int r = 0; r < 4; r++) { mI[r] = BIG_NEG; lI[r] = 0.0f; }

    // prologue: stage K(0) into buf 0
#pragma unroll
    for (int i = 0; i < 4; i++)
      async_cp16(kbase + (size_t)k_row[i] * KVD + k_col[i], &Ks[0][(wave * 4 + i) * 512]);

    for (int kt = 0; kt <= qt; kt++) {
      const int cur = kt & 1;
      const int k0 = kt * 64;
      __syncthreads();  // drains K(kt); all waves done with Vs(kt-1) reads

      // stage V(kt) + K(kt+1); drained at barrier-2 (hidden behind S+softmax)
#pragma unroll
      for (int i = 0; i < 4; i++)
        async_cp16(vbase + (size_t)v_row[i] * SEQ + k0 + v_col[i], &Vs[(wave * 4 + i) * 512]);
      if (kt < qt) {
        const int kn = k0 + 64;
#pragma unroll
        for (int i = 0; i < 4; i++)
          async_cp16(kbase + (size_t)(kn + k_row[i]) * KVD + k_col[i],
                     &Ks[cur ^ 1][(wave * 4 + i) * 512]);
      }

      // S = Q K^T (this wave: 16 rows of head h)
      floatx4 S[4] = {};
#pragma unroll
      for (int kk = 0; kk < 4; kk++)
#pragma unroll
        for (int nt = 0; nt < 4; nt++) {
          int row = nt * 16 + lrow;
          bf16x8 bk = *(const bf16x8*)&Ks[cur][row * 128 + ((kk * 4 + quad) ^ (row & 7)) * 8];
          S[nt] = __builtin_amdgcn_mfma_f32_16x16x32_bf16(aq[kk], bk, S[nt], 0, 0, 0);
        }

      if (kt == qt) {  // diagonal: causal mask
#pragma unroll
        for (int nt = 0; nt < 4; nt++) {
          int kj = nt * 16 + lrow;
#pragma unroll
          for (int r = 0; r < 4; r++) {
            int qi = wave * 16 + quad * 4 + r;
            if (kj > qi) S[nt][r] = BIG_NEG;
          }
        }
      }

      // online softmax (exp2 domain)
#pragma unroll
      for (int r = 0; r < 4; r++) {
        float mx = fmaxf(fmaxf(S[0][r], S[1][r]), fmaxf(S[2][r], S[3][r]));
        mx = fmaxf(mx, __shfl_xor(mx, 1));
        mx = fmaxf(mx, __shfl_xor(mx, 2));
        mx = fmaxf(mx, __shfl_xor(mx, 4));
        mx = fmaxf(mx, __shfl_xor(mx, 8));
        float mNew = fmaxf(mI[r], mx);
        float alpha = exp2f(mI[r] - mNew);
        float ssum = 0.0f;
#pragma unroll
        for (int nt = 0; nt < 4; nt++) {
          float p = exp2f(S[nt][r] - mNew);
          S[nt][r] = p;
          ssum += p;
        }
        ssum += __shfl_xor(ssum, 1);
        ssum += __shfl_xor(ssum, 2);
        ssum += __shfl_xor(ssum, 4);
        ssum += __shfl_xor(ssum, 8);
        lI[r] = lI[r] * alpha + ssum;
        mI[r] = mNew;
#pragma unroll
        for (int n2 = 0; n2 < 8; n2++) O[n2][r] *= alpha;
      }

      // P write: wave-private strip, swizzled chunks
#pragma unroll
      for (int nt = 0; nt < 4; nt++) {
        int cwr = ((nt * 2 + (lrow >> 3)) ^ (quad * 2)) * 8 + (lrow & 7);
#pragma unroll
        for (int r = 0; r < 4; r++)
          Ps[(wave * 16 + quad * 4 + r) * 72 + cwr] = bf16rn(S[nt][r]);
      }

      __syncthreads();  // drains V(kt) (+K(kt+1)); Vs ready

      // O += P V
#pragma unroll
      for (int kk = 0; kk < 2; kk++) {
        int capc = ((kk * 4 + quad) ^ (2 * ((lrow >> 2) & 3))) * 8;
        bf16x8 ap = *(const bf16x8*)&Ps[(wave * 16 + lrow) * 72 + capc];
#pragma unroll
        for (int n2 = 0; n2 < 8; n2++) {
          int row = n2 * 16 + lrow;
          bf16x8 bv = *(const bf16x8*)&Vs[row * 64 + ((kk * 4 + quad) ^ (row & 7)) * 8];
          O[n2] = __builtin_amdgcn_mfma_f32_16x16x32_bf16(ap, bv, O[n2], 0, 0, 0);
        }
      }
    }

    // epilogue: this wave's 16 rows x 128 dims of head h
#pragma unroll
    for (int n2 = 0; n2 < 8; n2++)
#pragma unroll
      for (int r = 0; r < 4; r++) {
        float val = O[n2][r] / lI[r];
        int row = q0 + wave * 16 + quad * 4 + r;
        int col = h * HD + n2 * 16 + lrow;
        yb[(size_t)(b * SEQ + row) * DIMN + col] = bf16rn(val);
      }
  }
}

// ----------------------------------------------------------------- launch
extern "C" void kernel_launch(void* const* d_in, const int* in_sizes, int n_in,
                              void* d_out, int out_size, void* d_ws, size_t ws_size,
                              hipStream_t stream) {
  const float* x      = (const float*)d_in[0];
  const float* q_gain = (const float*)d_in[1];
  const float* W_q    = (const float*)d_in[2];
  const float* W_k    = (const float*)d_in[3];
  const float* W_v    = (const float*)d_in[4];
  const float* W_proj = (const float*)d_in[5];
  float* out = (float*)d_out;
  char* ws = (char*)d_ws;

  short* xb    = (short*)(ws);                // MROWS*DIMN bf16   16.78 MB
  short* wqkv  = (short*)(ws + 16777216);     // NQKV*DIMN bf16    12.58 MB
  short* wproj = (short*)(ws + 29360128);     // DIMN*DIMN bf16     8.39 MB
  short* qkvb  = (short*)(ws + 37748736);     // MROWS*NQKV bf16   25.17 MB
  short* q     = (short*)(ws + 62914560);     // MROWS*DIMN bf16   16.78 MB
  short* k     = (short*)(ws + 79691776);     // MROWS*KVD bf16     4.19 MB
  short* vT    = (short*)(ws + 83886080);     // transposed V bf16  4.19 MB
  short* y     = xb;                          // alias: xb dead after QKV GEMM

  auto cvt = [&](const float* src, short* dst, int n) {
    int n8 = n / 8;
    f32_to_bf16_kern<<<(n8 + 255) / 256, 256, 0, stream>>>(src, dst, n8);
  };
  cvt(x, xb, MROWS * DIMN);
  cvt(W_q, wqkv, DIMN * DIMN);
  cvt(W_k, wqkv + DIMN * DIMN, KVD * DIMN);
  cvt(W_v, wqkv + DIMN * DIMN + KVD * DIMN, KVD * DIMN);
  cvt(W_proj, wproj, DIMN * DIMN);

  // qkv (bf16) = x @ [Wq;Wk;Wv]^T
  gemm_bt_as<short><<<dim3(NQKV / 128, MROWS / 128), 256, 0, stream>>>(xb, wqkv, qkvb, NQKV, DIMN);
  rms_rope_kern<<<(MROWS * 20) / 4, 256, 0, stream>>>(qkvb, q_gain, q, k);
  vT_kern<<<dim3(SEQ / 64, HD / 64, BATCH * NKVH), 256, 0, stream>>>(qkvb, vT);
  attn_kern<<<dim3(16, 32), 256, 0, stream>>>(q, k, vT, y);
  // out (f32) = y @ Wproj^T
  gemm_bt_as<float><<<dim3(DIMN / 128, MROWS / 128), 256, 0, stream>>>(y, wproj, out, DIMN, DIMN);
}